// Round 8
// baseline (342.776 us; speedup 1.0000x reference)
//
#include <hip/hip_runtime.h>

// Fused 10-iter screened-Laplace Jacobi, 2048^2 f32. Round 5 (3rd resubmit;
// rounds 5-7 benches never acquired a GPU).
// r4 diagnosis: VALU-issue ~14us (235 inst/iter/wave: edge cndmasks + addr
// arith) and occupancy LDS-capped at 2 blocks/CU (64KB dbuf tile).
// Fix: (1) halo-only LDS H[2][8][2][128] = 16KB -> 4 blocks/CU; rows live in
// registers, intra-wave exchange via __shfl(t^32), inter-wave via 1
// ds_read_b128 + 1 ds_write_b128 per iter. (2) body<EDGE> split: 810/940
// interior blocks skip all edge selects. (3) full 10-iter unroll -> LDS
// addresses fold to immediates. __launch_bounds__(512,8) forces <=64 VGPR.
// V_new = nsum(V)*R + B with R = mask?0:1/(4+relu(C)), B = mask?bc:0.

#define RES    2048
#define XHALO  12
#define YHALO  10
#define DIMX   128
#define DIMY   64
#define OUTX   (DIMX - 2*XHALO)            // 104
#define OUTY   (DIMY - 2*YHALO)            // 44
#define NBX    ((RES + OUTX - 1) / OUTX)   // 20
#define NBY    ((RES + OUTY - 1) / OUTY)   // 47
#define NWG    (NBX*NBY)                   // 940
#define NITER  10
#define HSTRIDE (8*2*DIMX)                 // floats per halo buffer

using HaloT = float[2][8][2][DIMX];        // 16,384 B

template<bool EDGE>
__device__ __forceinline__ void body(const int t, const int bx, const int by,
    const float* __restrict__ Xin, const float* __restrict__ Cin,
    const float* __restrict__ BTf, const float* __restrict__ BCin,
    float* __restrict__ OUT, float* __restrict__ CPOS, HaloT& H)
{
  const int  q      = t & 31;
  const int  ty     = t >> 5;          // 0..15, 4 rows each
  const int  w      = t >> 6;          // wave 0..7
  const bool tyEven = (ty & 1) == 0;
  const int  x0     = q * 4;
  const int  y0     = ty * 4;
  const int  tx0    = bx * OUTX - XHALO;
  const int  ty0    = by * OUTY - YHALO;
  const int  gx0    = tx0 + x0;        // multiple of 4 -> 16B aligned
  const int  gyr    = ty0 + y0;

  const bool xfull = !EDGE || ((gx0 >= 0) && (gx0 + 4 <= RES));
  const bool xin   = xfull && (x0 >= XHALO) && (x0 < XHALO + OUTX);

  // replicate-pad walls (only used when EDGE)
  const bool lq0 = EDGE && (gx0 + 0 <= 0);
  const bool lq1 = EDGE && (gx0 + 1 <= 0);
  const bool lq2 = EDGE && (gx0 + 2 <= 0);
  const bool lq3 = EDGE && (gx0 + 3 <= 0);
  const bool rq0 = EDGE && (gx0 + 0 >= RES - 1);
  const bool rq1 = EDGE && (gx0 + 1 >= RES - 1);
  const bool rq2 = EDGE && (gx0 + 2 >= RES - 1);
  const bool rq3 = EDGE && (gx0 + 3 >= RES - 1);

  auto load4 = [&](const float* __restrict__ g, int row) -> float4 {
    if constexpr (EDGE) {
      if (xfull) return *(const float4*)(g + (size_t)row * RES + gx0);
      const int xc = (gx0 < 0) ? 0 : (RES - 1);
      const float v = g[(size_t)row * RES + xc];
      return make_float4(v, v, v, v);
    } else {
      return *(const float4*)(g + (size_t)row * RES + gx0);
    }
  };

  // ---- staging: B, R (+CPOS), V0 rows -> registers ----
  float4 Bq[4], Rq[4], cur[4];
#pragma unroll
  for (int j = 0; j < 4; ++j) {
    const int yy = y0 + j;
    const int g  = gyr + j;
    const int gc = EDGE ? (g < 0 ? 0 : (g > RES - 1 ? RES - 1 : g)) : g;
    const float4 mv = load4(BTf, gc);
    const float4 bv = load4(BCin, gc);
    const float4 cv = load4(Cin, gc);
    const float4 xv = load4(Xin, gc);
    const bool m0 = __float_as_uint(mv.x) != 0u;
    const bool m1 = __float_as_uint(mv.y) != 0u;
    const bool m2 = __float_as_uint(mv.z) != 0u;
    const bool m3 = __float_as_uint(mv.w) != 0u;
    float4 B;
    B.x = m0 ? bv.x : 0.0f;  B.y = m1 ? bv.y : 0.0f;
    B.z = m2 ? bv.z : 0.0f;  B.w = m3 ? bv.w : 0.0f;
    Bq[j] = B;
    float4 cp;
    cp.x = cv.x > 0.0f ? cv.x : 0.0f;
    cp.y = cv.y > 0.0f ? cv.y : 0.0f;
    cp.z = cv.z > 0.0f ? cv.z : 0.0f;
    cp.w = cv.w > 0.0f ? cv.w : 0.0f;
    float4 R;
    R.x = m0 ? 0.0f : 1.0f / (4.0f + cp.x);
    R.y = m1 ? 0.0f : 1.0f / (4.0f + cp.y);
    R.z = m2 ? 0.0f : 1.0f / (4.0f + cp.z);
    R.w = m3 ? 0.0f : 1.0f / (4.0f + cp.w);
    Rq[j] = R;
    float4 v0;
    v0.x = m0 ? B.x : xv.x;  v0.y = m1 ? B.y : xv.y;
    v0.z = m2 ? B.z : xv.z;  v0.w = m3 ? B.w : xv.w;
    cur[j] = v0;
    if (xin && yy >= YHALO && yy < YHALO + OUTY && (!EDGE || g < RES)) {
      *(float4*)(CPOS + (size_t)g * RES + gx0) = cp;
    }
  }

  // halo plumbing: even ty reads wave w-1's bottom row (its row y0-1);
  // odd ty reads wave w+1's top row (its row y0+4). Clamped w -> rim garbage,
  // which stays outside the 10-iter validity trapezoid.
  const int wr = tyEven ? (w > 0 ? w - 1 : 0) : (w < 7 ? w + 1 : 7);
  float* const       hw = &H[0][w][tyEven ? 0 : 1][x0];
  const float* const hr = &H[0][wr][tyEven ? 1 : 0][x0];
  *(float4*)hw = tyEven ? cur[0] : cur[3];
  __syncthreads();

  auto rowstep = [&](int gy, const float4 R, const float4 B,
                     const float4 vp, const float4 vm, const float4 vn) -> float4 {
    const float lf = __shfl(vm.w, (t + 63) & 63);  // wrap garbage -> rim col only
    const float rt = __shfl(vm.x, (t + 1) & 63);
    float4 nv;
    if constexpr (EDGE) {
      const float4 va = (gy <= 0)       ? vm : vp;
      const float4 vb = (gy >= RES - 1) ? vm : vn;
      nv.x = fmaf(va.x + vb.x + (lq0 ? vm.x : lf)   + (rq0 ? vm.x : vm.y), R.x, B.x);
      nv.y = fmaf(va.y + vb.y + (lq1 ? vm.y : vm.x) + (rq1 ? vm.y : vm.z), R.y, B.y);
      nv.z = fmaf(va.z + vb.z + (lq2 ? vm.z : vm.y) + (rq2 ? vm.z : vm.w), R.z, B.z);
      nv.w = fmaf(va.w + vb.w + (lq3 ? vm.w : vm.z) + (rq3 ? vm.w : rt),   R.w, B.w);
    } else {
      nv.x = fmaf(vp.x + vn.x + lf   + vm.y, R.x, B.x);
      nv.y = fmaf(vp.y + vn.y + vm.x + vm.z, R.y, B.y);
      nv.z = fmaf(vp.z + vn.z + vm.y + vm.w, R.z, B.z);
      nv.w = fmaf(vp.w + vn.w + vm.z + rt,   R.w, B.w);
    }
    return nv;
  };

  // ---- 10 iterations, fully unrolled (LDS addrs fold to immediates) ----
#pragma unroll
  for (int it = 1; it <= NITER; ++it) {
    const int src = (it - 1) & 1;
    // intra-wave exchange of OLD boundary rows (even's row3 <-> odd's row0)
    const float4 snd = tyEven ? cur[3] : cur[0];
    float4 oth;
    oth.x = __shfl(snd.x, t ^ 32);
    oth.y = __shfl(snd.y, t ^ 32);
    oth.z = __shfl(snd.z, t ^ 32);
    oth.w = __shfl(snd.w, t ^ 32);
    const float4 hv = *(const float4*)(hr + src * HSTRIDE);
    const float4 P0 = tyEven ? hv : oth;   // row y0-1 (old)
    const float4 P3 = tyEven ? oth : hv;   // row y0+4 (old)
    const float4 n0 = rowstep(gyr + 0, Rq[0], Bq[0], P0,     cur[0], cur[1]);
    const float4 n1 = rowstep(gyr + 1, Rq[1], Bq[1], cur[0], cur[1], cur[2]);
    const float4 n2 = rowstep(gyr + 2, Rq[2], Bq[2], cur[1], cur[2], cur[3]);
    const float4 n3 = rowstep(gyr + 3, Rq[3], Bq[3], cur[2], cur[3], P3);
    cur[0] = n0; cur[1] = n1; cur[2] = n2; cur[3] = n3;
    if (it < NITER) {
      *(float4*)(hw + (it & 1) * HSTRIDE) = tyEven ? n0 : n3;
      __syncthreads();
    }
  }

  // ---- clamp epilogue straight from registers ----
#pragma unroll
  for (int j = 0; j < 4; ++j) {
    const int yy = y0 + j;
    const int g  = gyr + j;
    if (xin && yy >= YHALO && yy < YHALO + OUTY && (!EDGE || g < RES)) {
      const float4 nv = cur[j];
      float4 o;
      o.x = (nv.x >= 1.0f) ? 0.95f : nv.x;
      o.y = (nv.y >= 1.0f) ? 0.95f : nv.y;
      o.z = (nv.z >= 1.0f) ? 0.95f : nv.z;
      o.w = (nv.w >= 1.0f) ? 0.95f : nv.w;
      *(float4*)(OUT + (size_t)g * RES + gx0) = o;
    }
  }
}

__global__ __launch_bounds__(512, 8)
void laplace10_fused(const float* __restrict__ Xin,
                     const float* __restrict__ Cin,
                     const float* __restrict__ BTf,
                     const float* __restrict__ BCin,
                     float* __restrict__ OUT,
                     float* __restrict__ CPOS) {
  __shared__ __align__(16) float H[2][8][2][DIMX];   // 16 KB -> 4 blocks/CU

  const int t = threadIdx.x;
  // bijective XCD swizzle (NWG=940: qq=117, rr=4)
  int wg = (int)blockIdx.x;
  {
    const int qq = NWG / 8, rr = NWG % 8;
    const int xcd = wg % 8, off = wg / 8;
    wg = (xcd < rr ? xcd * (qq + 1) : rr * (qq + 1) + (xcd - rr) * qq) + off;
  }
  const int bx = wg % NBX, by = wg / NBX;

  if (bx > 0 && bx < NBX - 1 && by > 0 && by < NBY - 1) {
    body<false>(t, bx, by, Xin, Cin, BTf, BCin, OUT, CPOS, H);
  } else {
    body<true>(t, bx, by, Xin, Cin, BTf, BCin, OUT, CPOS, H);
  }
}

extern "C" void kernel_launch(void* const* d_in, const int* in_sizes, int n_in,
                              void* d_out, int out_size, void* d_ws, size_t ws_size,
                              hipStream_t stream) {
  const float* Xin  = (const float*)d_in[0];
  const float* Cin  = (const float*)d_in[1];
  const float* BTf  = (const float*)d_in[2];   // int32 bits, nonzero test only
  const float* BCin = (const float*)d_in[3];
  float* OUT  = (float*)d_out;
  float* CPOS = OUT + (size_t)RES * RES;

  hipLaunchKernelGGL(laplace10_fused, dim3(NWG), dim3(512), 0, stream,
                     Xin, Cin, BTf, BCin, OUT, CPOS);
}

// Round 12
// 258.842 us; speedup vs baseline: 1.3243x; 1.3243x over previous
//
#include <hip/hip_runtime.h>

// Fused 10-iter screened-Laplace Jacobi, 2048^2 f32. Round 9 (3rd resubmit;
// rounds 9-11 benches never acquired a GPU).
// r8 post-mortem: (512,8) forced VGPR cap 64 onto a ~90-live-value body ->
// VGPR=32, full spill cascade (WRITE 535MB vs 32MB output, VALUBusy 5%).
// Fix: make the live-set actually fit the 8-waves/EU tier: 1024-thread
// blocks, 2 rows/thread (state = Bq[2]+Rq[2]+cur[2] = 24 floats + temps
// ~= 45-55 VGPR under the 64 cap). 32 waves/CU (2 blocks x 16 waves).
// Halo-only LDS H[2][16][2][128] = 32KB; intra-wave row exchange via
// __shfl(t^32); inter-wave rows 4w-1 / 4w+4 via 1 ds_read_b128 +
// 1 ds_write_b128 per iter; 1 barrier/iter; rolled loop (low pressure).
// V_new = nsum(V)*R + B with R = mask?0:1/(4+relu(C)), B = mask?bc:0.
// Spill canary: VGPR must be <=64 with WRITE_SIZE ~= 33MB.

#define RES    2048
#define XHALO  12
#define YHALO  10
#define DIMX   128
#define DIMY   64
#define OUTX   (DIMX - 2*XHALO)            // 104
#define OUTY   (DIMY - 2*YHALO)            // 44
#define NBX    ((RES + OUTX - 1) / OUTX)   // 20
#define NBY    ((RES + OUTY - 1) / OUTY)   // 47
#define NWG    (NBX*NBY)                   // 940
#define NITER  10
#define NW     16                          // waves per block
#define HSTRIDE (NW*2*DIMX)                // floats per halo buffer

using HaloT = float[2][NW][2][DIMX];       // 32,768 B

template<bool EDGE>
__device__ __forceinline__ void body(const int t, const int bx, const int by,
    const float* __restrict__ Xin, const float* __restrict__ Cin,
    const float* __restrict__ BTf, const float* __restrict__ BCin,
    float* __restrict__ OUT, float* __restrict__ CPOS, HaloT& H)
{
  const int  q      = t & 31;
  const int  ty     = t >> 5;          // 0..31, 2 rows each
  const int  w      = t >> 6;          // wave 0..15 (rows 4w..4w+3)
  const bool tyEven = (ty & 1) == 0;
  const int  x0     = q * 4;
  const int  y0     = ty * 2;
  const int  tx0    = bx * OUTX - XHALO;
  const int  ty0    = by * OUTY - YHALO;
  const int  gx0    = tx0 + x0;        // multiple of 4 -> 16B aligned
  const int  gyr    = ty0 + y0;

  const bool xfull = !EDGE || ((gx0 >= 0) && (gx0 + 4 <= RES));
  const bool xin   = xfull && (x0 >= XHALO) && (x0 < XHALO + OUTX);

  // replicate-pad walls (only used when EDGE)
  const bool lq0 = EDGE && (gx0 + 0 <= 0);
  const bool lq1 = EDGE && (gx0 + 1 <= 0);
  const bool lq2 = EDGE && (gx0 + 2 <= 0);
  const bool lq3 = EDGE && (gx0 + 3 <= 0);
  const bool rq0 = EDGE && (gx0 + 0 >= RES - 1);
  const bool rq1 = EDGE && (gx0 + 1 >= RES - 1);
  const bool rq2 = EDGE && (gx0 + 2 >= RES - 1);
  const bool rq3 = EDGE && (gx0 + 3 >= RES - 1);

  auto load4 = [&](const float* __restrict__ g, int row) -> float4 {
    if constexpr (EDGE) {
      if (xfull) return *(const float4*)(g + (size_t)row * RES + gx0);
      const int xc = (gx0 < 0) ? 0 : (RES - 1);
      const float v = g[(size_t)row * RES + xc];
      return make_float4(v, v, v, v);
    } else {
      return *(const float4*)(g + (size_t)row * RES + gx0);
    }
  };

  // ---- staging: B, R (+CPOS), V0 rows -> registers ----
  float4 Bq[2], Rq[2], cur[2];
#pragma unroll
  for (int j = 0; j < 2; ++j) {
    const int yy = y0 + j;
    const int g  = gyr + j;
    const int gc = EDGE ? (g < 0 ? 0 : (g > RES - 1 ? RES - 1 : g)) : g;
    const float4 mv = load4(BTf, gc);
    const float4 bv = load4(BCin, gc);
    const float4 cv = load4(Cin, gc);
    const float4 xv = load4(Xin, gc);
    const bool m0 = __float_as_uint(mv.x) != 0u;
    const bool m1 = __float_as_uint(mv.y) != 0u;
    const bool m2 = __float_as_uint(mv.z) != 0u;
    const bool m3 = __float_as_uint(mv.w) != 0u;
    float4 B;
    B.x = m0 ? bv.x : 0.0f;  B.y = m1 ? bv.y : 0.0f;
    B.z = m2 ? bv.z : 0.0f;  B.w = m3 ? bv.w : 0.0f;
    Bq[j] = B;
    float4 cp;
    cp.x = cv.x > 0.0f ? cv.x : 0.0f;
    cp.y = cv.y > 0.0f ? cv.y : 0.0f;
    cp.z = cv.z > 0.0f ? cv.z : 0.0f;
    cp.w = cv.w > 0.0f ? cv.w : 0.0f;
    float4 R;
    R.x = m0 ? 0.0f : 1.0f / (4.0f + cp.x);
    R.y = m1 ? 0.0f : 1.0f / (4.0f + cp.y);
    R.z = m2 ? 0.0f : 1.0f / (4.0f + cp.z);
    R.w = m3 ? 0.0f : 1.0f / (4.0f + cp.w);
    Rq[j] = R;
    float4 v0;
    v0.x = m0 ? B.x : xv.x;  v0.y = m1 ? B.y : xv.y;
    v0.z = m2 ? B.z : xv.z;  v0.w = m3 ? B.w : xv.w;
    cur[j] = v0;
    if (xin && yy >= YHALO && yy < YHALO + OUTY && (!EDGE || g < RES)) {
      *(float4*)(CPOS + (size_t)g * RES + gx0) = cp;
    }
  }

  // halo slots: H[buf][w][0] = row 4w (even ty's cur[0]);
  //             H[buf][w][1] = row 4w+3 (odd ty's cur[1]).
  // even ty reads H[w-1][1] (row 4w-1); odd ty reads H[w+1][0] (row 4w+4).
  // Clamped w at wave 0/15 -> rim garbage, spreads 1 row/iter, stays inside
  // rows 0-9 / 54-63; output rows are 10-53.
  const int wr = tyEven ? (w > 0 ? w - 1 : 0) : (w < NW - 1 ? w + 1 : NW - 1);
  float* const       hw = &H[0][w][tyEven ? 0 : 1][x0];
  const float* const hr = &H[0][wr][tyEven ? 1 : 0][x0];
  *(float4*)hw = tyEven ? cur[0] : cur[1];
  __syncthreads();

  auto rowstep = [&](int gy, const float4 R, const float4 B,
                     const float4 vp, const float4 vm, const float4 vn) -> float4 {
    const float lf = __shfl(vm.w, (t + 63) & 63);  // wrap garbage -> rim col only
    const float rt = __shfl(vm.x, (t + 1) & 63);
    float4 nv;
    if constexpr (EDGE) {
      const float4 va = (gy <= 0)       ? vm : vp;
      const float4 vb = (gy >= RES - 1) ? vm : vn;
      nv.x = fmaf(va.x + vb.x + (lq0 ? vm.x : lf)   + (rq0 ? vm.x : vm.y), R.x, B.x);
      nv.y = fmaf(va.y + vb.y + (lq1 ? vm.y : vm.x) + (rq1 ? vm.y : vm.z), R.y, B.y);
      nv.z = fmaf(va.z + vb.z + (lq2 ? vm.z : vm.y) + (rq2 ? vm.z : vm.w), R.z, B.z);
      nv.w = fmaf(va.w + vb.w + (lq3 ? vm.w : vm.z) + (rq3 ? vm.w : rt),   R.w, B.w);
    } else {
      nv.x = fmaf(vp.x + vn.x + lf   + vm.y, R.x, B.x);
      nv.y = fmaf(vp.y + vn.y + vm.x + vm.z, R.y, B.y);
      nv.z = fmaf(vp.z + vn.z + vm.y + vm.w, R.z, B.z);
      nv.w = fmaf(vp.w + vn.w + vm.z + rt,   R.w, B.w);
    }
    return nv;
  };

  // ---- 10 iterations, rolled (minimal register pressure) ----
#pragma unroll 1
  for (int it = 1; it <= NITER; ++it) {
    // intra-wave exchange: even sends cur[1] (row 4w+1), odd sends cur[0]
    // (row 4w+2); t^32 swaps the ty pair within the wave at same column.
    const float4 snd = tyEven ? cur[1] : cur[0];
    float4 oth;
    oth.x = __shfl(snd.x, t ^ 32);
    oth.y = __shfl(snd.y, t ^ 32);
    oth.z = __shfl(snd.z, t ^ 32);
    oth.w = __shfl(snd.w, t ^ 32);
    const float4 hv = *(const float4*)(hr + ((it - 1) & 1) * HSTRIDE);
    const float4 P0 = tyEven ? hv : oth;   // row y0-1 (old)
    const float4 P1 = tyEven ? oth : hv;   // row y0+2 (old)
    const float4 n0 = rowstep(gyr + 0, Rq[0], Bq[0], P0,     cur[0], cur[1]);
    const float4 n1 = rowstep(gyr + 1, Rq[1], Bq[1], cur[0], cur[1], P1);
    cur[0] = n0; cur[1] = n1;
    if (it < NITER) {
      *(float4*)(hw + (it & 1) * HSTRIDE) = tyEven ? n0 : n1;
      __syncthreads();
    }
  }

  // ---- clamp epilogue straight from registers ----
#pragma unroll
  for (int j = 0; j < 2; ++j) {
    const int yy = y0 + j;
    const int g  = gyr + j;
    if (xin && yy >= YHALO && yy < YHALO + OUTY && (!EDGE || g < RES)) {
      const float4 nv = cur[j];
      float4 o;
      o.x = (nv.x >= 1.0f) ? 0.95f : nv.x;
      o.y = (nv.y >= 1.0f) ? 0.95f : nv.y;
      o.z = (nv.z >= 1.0f) ? 0.95f : nv.z;
      o.w = (nv.w >= 1.0f) ? 0.95f : nv.w;
      *(float4*)(OUT + (size_t)g * RES + gx0) = o;
    }
  }
}

__global__ __launch_bounds__(1024, 8)
void laplace10_fused(const float* __restrict__ Xin,
                     const float* __restrict__ Cin,
                     const float* __restrict__ BTf,
                     const float* __restrict__ BCin,
                     float* __restrict__ OUT,
                     float* __restrict__ CPOS) {
  __shared__ __align__(16) float H[2][NW][2][DIMX];   // 32 KB

  const int t = threadIdx.x;
  // bijective XCD swizzle (NWG=940: qq=117, rr=4)
  int wg = (int)blockIdx.x;
  {
    const int qq = NWG / 8, rr = NWG % 8;
    const int xcd = wg % 8, off = wg / 8;
    wg = (xcd < rr ? xcd * (qq + 1) : rr * (qq + 1) + (xcd - rr) * qq) + off;
  }
  const int bx = wg % NBX, by = wg / NBX;

  if (bx > 0 && bx < NBX - 1 && by > 0 && by < NBY - 1) {
    body<false>(t, bx, by, Xin, Cin, BTf, BCin, OUT, CPOS, H);
  } else {
    body<true>(t, bx, by, Xin, Cin, BTf, BCin, OUT, CPOS, H);
  }
}

extern "C" void kernel_launch(void* const* d_in, const int* in_sizes, int n_in,
                              void* d_out, int out_size, void* d_ws, size_t ws_size,
                              hipStream_t stream) {
  const float* Xin  = (const float*)d_in[0];
  const float* Cin  = (const float*)d_in[1];
  const float* BTf  = (const float*)d_in[2];   // int32 bits, nonzero test only
  const float* BCin = (const float*)d_in[3];
  float* OUT  = (float*)d_out;
  float* CPOS = OUT + (size_t)RES * RES;

  hipLaunchKernelGGL(laplace10_fused, dim3(NWG), dim3(1024), 0, stream,
                     Xin, Cin, BTf, BCin, OUT, CPOS);
}